// Round 1
// baseline (1069.700 us; speedup 1.0000x reference)
//
#include <hip/hip_runtime.h>

// ---------------------------------------------------------------- types/helpers
using frag_ab = __attribute__((ext_vector_type(8))) short;   // bf16x8 MFMA operand
using f4v     = __attribute__((ext_vector_type(4))) float;   // MFMA accumulator
using u8v     = __attribute__((ext_vector_type(8))) unsigned short;
using u4v     = __attribute__((ext_vector_type(4))) unsigned short;

__device__ __forceinline__ float b2f(unsigned short u){
  return __uint_as_float(((unsigned int)u) << 16);
}
__device__ __forceinline__ unsigned short f2b(float f){
  unsigned int x = __float_as_uint(f);
  unsigned int r = x + 0x7fffu + ((x >> 16) & 1u);
  return (unsigned short)(r >> 16);
}

#define MFMA_BF16 __builtin_amdgcn_mfma_f32_16x16x32_bf16

// ---------------------------------------------------------------- ws layout (bytes)
static constexpr size_t OFF_T   = 0;                       // t f32 [32768][256]           33,554,432
static constexpr size_t OFF_R1  = 33554432ull;             // im2col | q+k | g (mlp hidden)
static constexpr size_t OFF_V   = OFF_R1 + 37748736ull;    // v | o2                       16,777,216
static constexpr size_t OFF_VT  = OFF_V + 16777216ull;     // vT | logits f32              16,777,216
static constexpr size_t OFF_ZH  = OFF_VT + 16777216ull;    // zwin | o | h                 16,777,216
static constexpr size_t OFF_A   = OFF_ZH + 16777216ull;    // a bf16 [32768][128]           8,388,608
static constexpr size_t OFF_WB  = OFF_A + 8388608ull;      // converted weights
// weight sub-offsets (bytes from OFF_WB)
static constexpr size_t WB_CONVW = 0;          // 256*576*2        =   294,912
static constexpr size_t WB_QKVW  = 294912;     // 4*768*256*2      = 1,572,864
static constexpr size_t WB_PROJW = 1867776;    // 4*256*256*2      =   524,288
static constexpr size_t WB_MLP1W = 2392064;    // 4*512*256*2      = 1,048,576
static constexpr size_t WB_MLP2W = 3440640;    // 4*256*512*2      = 1,048,576
static constexpr size_t WB_W1    = 4489216;    // 4*128*256*2      =   262,144
static constexpr size_t WB_W2T   = 4751360;    // 4*256*128*2      =   262,144
static constexpr size_t WB_BLOG  = 5013504;    // 4*128*4 f32      =     2,048
static constexpr size_t WB_CS    = 5015552;    // 256 f32
static constexpr size_t WB_CSH   = 5016576;    // 256 f32
static constexpr size_t WB_BIAST = 5017600;    // 4*4*256*256*2    = 2,097,152

// ---------------------------------------------------------------- prep: weight converts + folded mats + bias table
__global__ __launch_bounds__(256) void prep_k(
    const float* __restrict__ conv_w, const float* __restrict__ bn_g, const float* __restrict__ bn_b,
    const float* __restrict__ bn_m, const float* __restrict__ bn_v,
    const float* __restrict__ qkv_w, const float* __restrict__ proj_w,
    const float* __restrict__ mlp_w1, const float* __restrict__ mlp_w2,
    const float* __restrict__ mem_b, const float* __restrict__ down_w, const float* __restrict__ down_b,
    const float* __restrict__ up_w, const float* __restrict__ rpb,
    unsigned short* convwb, unsigned short* qkvwb, unsigned short* projwb,
    unsigned short* mlp1wb, unsigned short* mlp2wb, unsigned short* W1b, unsigned short* W2Tb,
    unsigned short* biasTb, float* blogf, float* convS, float* convSh)
{
  int idx = blockIdx.x * 256 + threadIdx.x;
  if (idx < 256){
    float s = bn_g[idx] * rsqrtf(bn_v[idx] + 1e-5f);
    convS[idx] = s; convSh[idx] = bn_b[idx] - bn_m[idx] * s; return;
  }
  idx -= 256;
  if (idx < 147456){  // conv weight reorder: [co][ci*9+ky*3+kx]
    int co = idx / 576, kk = idx % 576;
    int ci = kk / 9, t9 = kk % 9, ky = t9 / 3, kx = t9 % 3;
    convwb[idx] = f2b(conv_w[((co*64 + ci)*3 + ky)*3 + kx]); return;
  }
  idx -= 147456;
  if (idx < 786432){ qkvwb[idx] = f2b(qkv_w[idx]); return; }
  idx -= 786432;
  if (idx < 262144){ projwb[idx] = f2b(proj_w[idx]); return; }
  idx -= 262144;
  if (idx < 524288){ mlp1wb[idx] = f2b(mlp_w1[idx]); return; }
  idx -= 524288;
  if (idx < 524288){ mlp2wb[idx] = f2b(mlp_w2[idx]); return; }
  idx -= 524288;
  if (idx < 131072){  // W1[i][s][c] = sum_j mem[i][s][j]*down[i][j][c]
    int i = idx >> 15, rem = idx & 32767, s = rem >> 8, c = rem & 255;
    float acc = 0.f;
    for (int j = 0; j < 32; ++j) acc += mem_b[(i*128 + s)*32 + j] * down_w[(i*32 + j)*256 + c];
    W1b[idx] = f2b(acc); return;
  }
  idx -= 131072;
  if (idx < 131072){  // W2T[i][c][s] = sum_j mem[i][s][j]*up[i][c][j]
    int i = idx >> 15, rem = idx & 32767, c = rem >> 7, s = rem & 127;
    float acc = 0.f;
    for (int j = 0; j < 32; ++j) acc += mem_b[(i*128 + s)*32 + j] * up_w[(i*256 + c)*32 + j];
    W2Tb[idx] = f2b(acc); return;
  }
  idx -= 131072;
  if (idx < 512){  // blog[i][s] = mem[i][s]·down_b[i]
    int i = idx >> 7, s = idx & 127;
    float acc = 0.f;
    for (int j = 0; j < 32; ++j) acc += mem_b[(i*128 + s)*32 + j] * down_b[i*32 + j];
    blogf[idx] = acc; return;
  }
  idx -= 512;
  if (idx < 1048576){  // biasT[i][h][m][n] = rpb[i][rpi[n][m]][h]
    int i = idx >> 18, h = (idx >> 16) & 3, m = (idx >> 8) & 255, n = idx & 255;
    int rn = n >> 4, cn = n & 15, rm = m >> 4, cm = m & 15;
    int ri = (rn - rm + 15)*31 + (cn - cm + 15);
    biasTb[idx] = f2b(rpb[((size_t)i*961 + ri)*4 + h]);
  }
}

// ---------------------------------------------------------------- im2col (k-order ci*9+ky*3+kx), f32 -> bf16
__global__ __launch_bounds__(256) void im2col_k(const float* __restrict__ x, unsigned short* __restrict__ col)
{
  int idx = blockIdx.x * 256 + threadIdx.x;   // 32768*576
  if (idx >= 32768*576) return;
  int row = idx / 576, kk = idx % 576;
  int ci = kk / 9, t9 = kk % 9, ky = t9 / 3, kx = t9 % 3;
  int b = row >> 12, hh = (row >> 6) & 63, wp = row & 63;
  int h2 = hh + ky - 1, w2 = wp + kx - 1;
  float v = 0.f;
  if (h2 >= 0 && h2 < 64 && w2 >= 0 && w2 < 64) v = x[((b*64 + ci)*64 + h2)*64 + w2];
  col[idx] = f2b(v);
}

// ---------------------------------------------------------------- GEMM: Y[M=32768,N] = X[M,K](bf16) @ W[N,K]^T(bf16), fused epilogues
struct EpArgs {
  const float* b0; const float* b1;
  float* f0;
  unsigned short* u0; unsigned short* u1; unsigned short* u2;
  const unsigned short* uin;
  int shift;
};
enum { M_CONV=0, M_QKV=1, M_MEM1=2, M_MEM2=3, M_PROJ=4, M_MLP1=5, M_MLP2=6 };

template<int MODE>
__global__ __launch_bounds__(256) void gemm_k(const unsigned short* __restrict__ X,
                                              const unsigned short* __restrict__ W,
                                              int K, EpArgs ep)
{
  __shared__ unsigned short Als[128*32];
  __shared__ unsigned short Bls[128*32];
  const int tid = threadIdx.x;
  const int wid = tid >> 6, lane = tid & 63, g = lane >> 4, l15 = lane & 15;
  const int wr = wid >> 1, wc = wid & 1;
  const int row0 = blockIdx.x * 128, col0 = blockIdx.y * 128;
  const int KT = K >> 5;
  const int s0 = tid, s1 = tid + 256;

  auto ldA = [&](int s, int kt) -> u8v {
    int r = s >> 2, p = s & 3, lb = p ^ ((r >> 1) & 3);
    return *(const u8v*)&X[(size_t)(row0 + r)*K + kt*32 + lb*8];
  };
  auto ldB = [&](int s, int kt) -> u8v {
    int r = s >> 2, p = s & 3, lb = p ^ ((r >> 1) & 3);
    return *(const u8v*)&W[(size_t)(col0 + r)*K + kt*32 + lb*8];
  };

  u8v a0 = ldA(s0,0), a1 = ldA(s1,0), b0 = ldB(s0,0), b1 = ldB(s1,0);
  f4v acc[4][4] = {};

  for (int kt = 0; kt < KT; ++kt){
    __syncthreads();
    *(u8v*)&Als[s0*8] = a0; *(u8v*)&Als[s1*8] = a1;
    *(u8v*)&Bls[s0*8] = b0; *(u8v*)&Bls[s1*8] = b1;
    __syncthreads();
    if (kt + 1 < KT){ a0 = ldA(s0,kt+1); a1 = ldA(s1,kt+1); b0 = ldB(s0,kt+1); b1 = ldB(s1,kt+1); }
    frag_ab af[4], bfv[4];
    #pragma unroll
    for (int a = 0; a < 4; ++a){ int r = wr*64 + a*16 + l15; int pb = g ^ ((r >> 1) & 3);
      af[a] = *(const frag_ab*)&Als[r*32 + pb*8]; }
    #pragma unroll
    for (int b = 0; b < 4; ++b){ int r = wc*64 + b*16 + l15; int pb = g ^ ((r >> 1) & 3);
      bfv[b] = *(const frag_ab*)&Bls[r*32 + pb*8]; }
    #pragma unroll
    for (int a = 0; a < 4; ++a)
      #pragma unroll
      for (int b = 0; b < 4; ++b)
        acc[a][b] = MFMA_BF16(af[a], bfv[b], acc[a][b], 0, 0, 0);
  }

  #pragma unroll
  for (int a = 0; a < 4; ++a){
    #pragma unroll
    for (int b = 0; b < 4; ++b){
      #pragma unroll
      for (int r = 0; r < 4; ++r){
        int grow = row0 + wr*64 + a*16 + g*4 + r;
        int gcol = col0 + wc*64 + b*16 + l15;
        float v = acc[a][b][r];
        if constexpr (MODE == M_CONV){
          float vb = fmaxf(v * ep.b0[gcol] + ep.b1[gcol], 0.f);
          ep.f0[(size_t)grow*256 + gcol] = vb;
        } else if constexpr (MODE == M_QKV){
          float vb = v + ep.b0[gcol];
          int which = gcol >> 8, hh = (gcol >> 6) & 3, hd = gcol & 63;
          if (which == 0) vb *= 0.125f;
          unsigned short* dst = (which == 0) ? ep.u0 : ((which == 1) ? ep.u1 : ep.u2);
          dst[(((size_t)(grow >> 8)*4 + hh)*256 + (grow & 255))*64 + hd] = f2b(vb);
        } else if constexpr (MODE == M_MEM1){
          ep.f0[(size_t)grow*128 + gcol] = v + ep.b0[gcol];
        } else if constexpr (MODE == M_MEM2){
          size_t ix = (size_t)grow*256 + gcol;
          ep.u0[ix] = f2b(b2f(ep.uin[ix]) + 0.1f*(v + ep.b0[gcol]));
        } else if constexpr (MODE == M_PROJ){
          float vb = v + ep.b0[gcol];
          int win = grow >> 8, tok = grow & 255;
          int bb = win >> 4, wh = (win >> 2) & 3, ww = win & 3, rr = tok >> 4, cc = tok & 15;
          int h = (wh*16 + rr + ep.shift) & 63, w2 = (ww*16 + cc + ep.shift) & 63;
          size_t ix = ((size_t)((bb*64 + h)*64 + w2))*256 + gcol;
          ep.f0[ix] += vb;
        } else if constexpr (MODE == M_MLP1){
          float xq = v + ep.b0[gcol];
          float gl = 0.5f*xq*(1.f + tanhf(0.7978845608f*(xq + 0.044715f*xq*xq*xq)));
          ep.u0[(size_t)grow*512 + gcol] = f2b(gl);
        } else { // M_MLP2
          ep.f0[(size_t)grow*256 + gcol] += v + ep.b0[gcol];
        }
      }
    }
  }
}

// ---------------------------------------------------------------- LayerNorm (wave per token), optional roll+window gather
__global__ __launch_bounds__(256) void ln_k(const float* __restrict__ t, const float* __restrict__ gw,
    const float* __restrict__ bw, unsigned short* __restrict__ o, int windowed, int shift)
{
  int row = blockIdx.x*4 + (threadIdx.x >> 6);
  int lane = threadIdx.x & 63;
  size_t src;
  if (windowed){
    int win = row >> 8, tok = row & 255;
    int b = win >> 4, wh = (win >> 2) & 3, ww = win & 3, r = tok >> 4, c = tok & 15;
    int h = (wh*16 + r + shift) & 63, w2 = (ww*16 + c + shift) & 63;
    src = ((size_t)((b*64 + h)*64 + w2))*256;
  } else {
    src = (size_t)row*256;
  }
  float4 x = *(const float4*)&t[src + lane*4];
  float s1 = x.x + x.y + x.z + x.w;
  float s2 = x.x*x.x + x.y*x.y + x.z*x.z + x.w*x.w;
  #pragma unroll
  for (int d = 1; d < 64; d <<= 1){ s1 += __shfl_xor(s1, d); s2 += __shfl_xor(s2, d); }
  float mu = s1 * (1.0f/256.0f);
  float var = s2 * (1.0f/256.0f) - mu*mu;
  float rs = rsqrtf(var + 1e-5f);
  int c0 = lane*4;
  float xs[4] = {x.x, x.y, x.z, x.w};
  u4v ov;
  #pragma unroll
  for (int e = 0; e < 4; ++e) ov[e] = f2b((xs[e]-mu)*rs*gw[c0+e] + bw[c0+e]);
  *(u4v*)&o[(size_t)row*256 + c0] = ov;
}

// ---------------------------------------------------------------- V transpose per (win,head): [256 tok][64 hd] -> [64 hd][256 tok]
__global__ __launch_bounds__(256) void trv_k(const unsigned short* __restrict__ v, unsigned short* __restrict__ vt)
{
  __shared__ unsigned short lv[16384];
  int blk = blockIdx.x, tid = threadIdx.x;
  const unsigned short* src = v + (size_t)blk*16384;
  unsigned short* dst = vt + (size_t)blk*16384;
  #pragma unroll
  for (int it = 0; it < 8; ++it){ int s = it*256 + tid; *(u8v*)&lv[s*8] = *(const u8v*)&src[s*8]; }
  __syncthreads();
  int hd = tid >> 2, t0 = (tid & 3)*64;
  for (int tt = 0; tt < 64; tt += 8){
    u8v o;
    #pragma unroll
    for (int e = 0; e < 8; ++e) o[e] = lv[(t0 + tt + e)*64 + hd];
    *(u8v*)&dst[hd*256 + t0 + tt] = o;
  }
}

// ---------------------------------------------------------------- windowed attention, one block per (win,head), 4 waves
// S^T = mfma(K, Q) so each lane owns one query column; softmax per-lane + 2 shuffles; PV in-register.
__global__ __launch_bounds__(256) void attn_k(const unsigned short* __restrict__ qg_,
    const unsigned short* __restrict__ kg_, const unsigned short* __restrict__ vg_,
    const unsigned short* __restrict__ biasT, unsigned short* __restrict__ ob, int shift)
{
  __shared__ unsigned short Kl[16384];   // [256 tok][64 hd], blocks of 8 elems XOR-swizzled by row&7
  __shared__ unsigned short Vl[16384];   // [64 hd][256 tok], low-4 block bits XOR hd&15
  const int tid = threadIdx.x, wid = tid >> 6, lane = tid & 63, g = lane >> 4, q15 = lane & 15;
  const int blk = blockIdx.x, win = blk >> 2, head = blk & 3;
  const int wh = (win >> 2) & 3, ww = win & 3;
  const unsigned short* kg = kg_ + (size_t)blk*16384;
  const unsigned short* vg = vg_ + (size_t)blk*16384;
  const unsigned short* qg = qg_ + (size_t)blk*16384;
  const unsigned short* bT = biasT + ((size_t)head << 16);

  #pragma unroll
  for (int it = 0; it < 8; ++it){
    int s = it*256 + tid;
    { int r = s >> 3, lb = (s & 7) ^ (r & 7);
      *(u8v*)&Kl[s*8] = *(const u8v*)&kg[r*64 + lb*8]; }
    { int hd = s >> 5, p = s & 31, lb = (p & 16) | ((p & 15) ^ (hd & 15));
      *(u8v*)&Vl[s*8] = *(const u8v*)&vg[hd*256 + lb*8]; }
  }
  __syncthreads();

  const f4v Z4 = {0.f, 0.f, 0.f, 0.f};
  const int qb0w = wid*64;
  for (int c = 0; c < 4; ++c){
    const int nq = qb0w + c*16 + q15;         // this lane's query token
    const int rn = nq >> 4, cn = nq & 15;
    int cntn = 0;
    if (shift){
      int ah = (wh == 3) ? ((rn < 8) ? 1 : 2) : 0;
      int aw = (ww == 3) ? ((cn < 8) ? 1 : 2) : 0;
      cntn = ah*3 + aw;
    }
    frag_ab qf0 = *(const frag_ab*)&qg[nq*64 + g*8];
    frag_ab qf1 = *(const frag_ab*)&qg[nq*64 + 32 + g*8];
    f4v acc[16];
    #pragma unroll
    for (int t2 = 0; t2 < 16; ++t2) acc[t2] = Z4;
    #pragma unroll
    for (int t2 = 0; t2 < 16; ++t2){
      int r = t2*16 + q15;
      { int pb = g ^ (r & 7);
        frag_ab ak = *(const frag_ab*)&Kl[r*64 + pb*8];
        acc[t2] = MFMA_BF16(ak, qf0, acc[t2], 0, 0, 0); }
      { int pb = (4 + g) ^ (r & 7);
        frag_ab ak = *(const frag_ab*)&Kl[r*64 + pb*8];
        acc[t2] = MFMA_BF16(ak, qf1, acc[t2], 0, 0, 0); }
    }
    // bias + mask + softmax (lane owns query nq; its 64 key entries are k = t2*16 + g*4 + r)
    float vmax = -3.0e38f;
    #pragma unroll
    for (int t2 = 0; t2 < 16; ++t2){
      int bh3 = 0;
      if (shift) bh3 = ((wh == 3) ? ((t2 < 8) ? 1 : 2) : 0) * 3;
      #pragma unroll
      for (int r = 0; r < 4; ++r){
        int cm = g*4 + r;
        float vv = acc[t2][r] + b2f(bT[(t2*16 + cm)*256 + nq]);
        if (shift){
          int bw = (ww == 3) ? ((cm < 8) ? 1 : 2) : 0;
          vv += (bh3 + bw != cntn) ? -100.0f : 0.0f;
        }
        acc[t2][r] = vv;
        vmax = fmaxf(vmax, vv);
      }
    }
    vmax = fmaxf(vmax, __shfl_xor(vmax, 16));
    vmax = fmaxf(vmax, __shfl_xor(vmax, 32));
    float vsum = 0.f;
    #pragma unroll
    for (int t2 = 0; t2 < 16; ++t2)
      #pragma unroll
      for (int r = 0; r < 4; ++r){
        float p = exp2f((acc[t2][r] - vmax) * 1.44269504f);
        acc[t2][r] = p; vsum += p;
      }
    vsum += __shfl_xor(vsum, 16);
    vsum += __shfl_xor(vsum, 32);
    float inv = 1.0f / vsum;
    float invl[4];
    #pragma unroll
    for (int r = 0; r < 4; ++r) invl[r] = __shfl(inv, g*4 + r);
    // PV: A = P (row = q), consistent k-permutation with V fragments from swizzled Vl
    f4v oc[4];
    #pragma unroll
    for (int nn = 0; nn < 4; ++nn) oc[nn] = Z4;
    #pragma unroll
    for (int s = 0; s < 8; ++s){
      frag_ab pa;
      #pragma unroll
      for (int j = 0; j < 4; ++j){
        pa[j]     = (short)f2b(acc[2*s][j]);
        pa[j + 4] = (short)f2b(acc[2*s + 1][j]);
      }
      #pragma unroll
      for (int nn = 0; nn < 4; ++nn){
        int hd = nn*16 + q15;
        int blkA = 4*s + (g >> 1);
        int pbA = ((blkA ^ (hd & 15)) & 15) | (blkA & 16);
        int blkB = blkA + 2;
        int pbB = ((blkB ^ (hd & 15)) & 15) | (blkB & 16);
        int sub = (g & 1)*4;
        u4v lo = *(const u4v*)&Vl[hd*256 + pbA*8 + sub];
        u4v hi = *(const u4v*)&Vl[hd*256 + pbB*8 + sub];
        frag_ab bv;
        #pragma unroll
        for (int e = 0; e < 4; ++e){ bv[e] = (short)lo[e]; bv[e + 4] = (short)hi[e]; }
        oc[nn] = MFMA_BF16(pa, bv, oc[nn], 0, 0, 0);
      }
    }
    #pragma unroll
    for (int nn = 0; nn < 4; ++nn)
      #pragma unroll
      for (int r = 0; r < 4; ++r){
        int qq = qb0w + c*16 + g*4 + r;
        ob[((size_t)(win*256 + qq))*256 + head*64 + nn*16 + q15] = f2b(oc[nn][r] * invl[r]);
      }
  }
}

// ---------------------------------------------------------------- softmax over 128 memory slots, wave per token
__global__ __launch_bounds__(256) void sm128_k(const float* __restrict__ lg, unsigned short* __restrict__ a)
{
  int row = blockIdx.x*4 + (threadIdx.x >> 6), lane = threadIdx.x & 63;
  float2 lv = *(const float2*)&lg[(size_t)row*128 + lane*2];
  float m = fmaxf(lv.x, lv.y);
  #pragma unroll
  for (int d = 1; d < 64; d <<= 1) m = fmaxf(m, __shfl_xor(m, d));
  float e0 = exp2f((lv.x - m)*1.44269504f), e1 = exp2f((lv.y - m)*1.44269504f);
  float s = e0 + e1;
  #pragma unroll
  for (int d = 1; d < 64; d <<= 1) s += __shfl_xor(s, d);
  float inv = 1.0f / s;
  unsigned int pack = ((unsigned int)f2b(e1*inv) << 16) | f2b(e0*inv);
  *(unsigned int*)&a[(size_t)row*128 + lane*2] = pack;
}

// ---------------------------------------------------------------- final NHWC f32 -> NCHW f32
__global__ __launch_bounds__(256) void nchw_k(const float* __restrict__ t, float* __restrict__ out)
{
  __shared__ float ls[64*65];
  int bh = blockIdx.x; int b = bh >> 6, h = bh & 63; int tid = threadIdx.x;
  for (int c0 = 0; c0 < 256; c0 += 64){
    #pragma unroll
    for (int rr = 0; rr < 4; ++rr){
      int s = rr*256 + tid;
      int w = s >> 4, c4 = s & 15;
      float4 v = *(const float4*)&t[((size_t)((b*64 + h)*64 + w))*256 + c0 + c4*4];
      ls[w*65 + c4*4 + 0] = v.x; ls[w*65 + c4*4 + 1] = v.y;
      ls[w*65 + c4*4 + 2] = v.z; ls[w*65 + c4*4 + 3] = v.w;
    }
    __syncthreads();
    int c = tid & 63, wq = tid >> 6;
    float buf[16];
    #pragma unroll
    for (int k2 = 0; k2 < 16; ++k2) buf[k2] = ls[(wq*16 + k2)*65 + c];
    size_t obase = ((size_t)(b*256 + c0 + c))*4096 + h*64 + wq*16;
    #pragma unroll
    for (int k2 = 0; k2 < 16; k2 += 4){
      float4 o4 = make_float4(buf[k2], buf[k2+1], buf[k2+2], buf[k2+3]);
      *(float4*)&out[obase + k2] = o4;
    }
    __syncthreads();
  }
}

// ---------------------------------------------------------------- host
extern "C" void kernel_launch(void* const* d_in, const int* in_sizes, int n_in,
                              void* d_out, int out_size, void* d_ws, size_t ws_size,
                              hipStream_t stream)
{
  (void)in_sizes; (void)n_in; (void)out_size; (void)ws_size;
  const float* x      = (const float*)d_in[0];
  const float* conv_w = (const float*)d_in[1];
  const float* bn_g   = (const float*)d_in[2];
  const float* bn_b   = (const float*)d_in[3];
  const float* bn_m   = (const float*)d_in[4];
  const float* bn_v   = (const float*)d_in[5];
  const float* ln1_g  = (const float*)d_in[6];
  const float* ln1_b  = (const float*)d_in[7];
  const float* qkv_w  = (const float*)d_in[8];
  const float* qkv_b  = (const float*)d_in[9];
  const float* proj_w = (const float*)d_in[10];
  const float* proj_b = (const float*)d_in[11];
  const float* rpb    = (const float*)d_in[12];
  const float* mem_b  = (const float*)d_in[13];
  const float* down_w = (const float*)d_in[14];
  const float* down_b = (const float*)d_in[15];
  const float* up_w   = (const float*)d_in[16];
  const float* up_b   = (const float*)d_in[17];
  const float* ln2_g  = (const float*)d_in[18];
  const float* ln2_b  = (const float*)d_in[19];
  const float* mlp_w1 = (const float*)d_in[20];
  const float* mlp_b1 = (const float*)d_in[21];
  const float* mlp_w2 = (const float*)d_in[22];
  const float* mlp_b2 = (const float*)d_in[23];

  char* ws = (char*)d_ws;
  float*          tbuf  = (float*)(ws + OFF_T);
  unsigned short* colb  = (unsigned short*)(ws + OFF_R1);
  unsigned short* qbuf  = (unsigned short*)(ws + OFF_R1);
  unsigned short* kbuf  = (unsigned short*)(ws + OFF_R1 + 16777216ull);
  unsigned short* gbuf  = (unsigned short*)(ws + OFF_R1);
  unsigned short* vbuf  = (unsigned short*)(ws + OFF_V);
  unsigned short* o2buf = (unsigned short*)(ws + OFF_V);
  unsigned short* vtbuf = (unsigned short*)(ws + OFF_VT);
  float*          logb  = (float*)(ws + OFF_VT);
  unsigned short* zbuf  = (unsigned short*)(ws + OFF_ZH);  // zwin | o | h
  unsigned short* abuf  = (unsigned short*)(ws + OFF_A);
  unsigned short* convwb = (unsigned short*)(ws + OFF_WB + WB_CONVW);
  unsigned short* qkvwb  = (unsigned short*)(ws + OFF_WB + WB_QKVW);
  unsigned short* projwb = (unsigned short*)(ws + OFF_WB + WB_PROJW);
  unsigned short* mlp1wb = (unsigned short*)(ws + OFF_WB + WB_MLP1W);
  unsigned short* mlp2wb = (unsigned short*)(ws + OFF_WB + WB_MLP2W);
  unsigned short* W1b    = (unsigned short*)(ws + OFF_WB + WB_W1);
  unsigned short* W2Tb   = (unsigned short*)(ws + OFF_WB + WB_W2T);
  float*          blogf  = (float*)(ws + OFF_WB + WB_BLOG);
  float*          convS  = (float*)(ws + OFF_WB + WB_CS);
  float*          convSh = (float*)(ws + OFF_WB + WB_CSH);
  unsigned short* biasTb = (unsigned short*)(ws + OFF_WB + WB_BIAST);

  prep_k<<<13891, 256, 0, stream>>>(conv_w, bn_g, bn_b, bn_m, bn_v, qkv_w, proj_w, mlp_w1, mlp_w2,
                                    mem_b, down_w, down_b, up_w, rpb,
                                    convwb, qkvwb, projwb, mlp1wb, mlp2wb, W1b, W2Tb, biasTb,
                                    blogf, convS, convSh);
  im2col_k<<<73728, 256, 0, stream>>>(x, colb);
  { EpArgs ep{convS, convSh, tbuf, nullptr, nullptr, nullptr, nullptr, 0};
    gemm_k<M_CONV><<<dim3(256,2), 256, 0, stream>>>(colb, convwb, 576, ep); }

  for (int i = 0; i < 4; ++i){
    int shift = (i & 1) ? 8 : 0;
    ln_k<<<8192, 256, 0, stream>>>(tbuf, ln1_g + i*256, ln1_b + i*256, zbuf, 1, shift);
    { EpArgs ep{qkv_b + i*768, nullptr, nullptr, qbuf, kbuf, vbuf, nullptr, 0};
      gemm_k<M_QKV><<<dim3(256,6), 256, 0, stream>>>(zbuf, qkvwb + (size_t)i*196608, 256, ep); }
    trv_k<<<512, 256, 0, stream>>>(vbuf, vtbuf);
    attn_k<<<512, 256, 0, stream>>>(qbuf, kbuf, vtbuf, biasTb + ((size_t)i << 18), zbuf, shift);
    { EpArgs ep{blogf + i*128, nullptr, logb, nullptr, nullptr, nullptr, nullptr, 0};
      gemm_k<M_MEM1><<<dim3(256,1), 256, 0, stream>>>(zbuf, W1b + (size_t)i*32768, 256, ep); }
    sm128_k<<<8192, 256, 0, stream>>>(logb, abuf);
    { EpArgs ep{up_b + i*256, nullptr, nullptr, o2buf, nullptr, nullptr, zbuf, 0};
      gemm_k<M_MEM2><<<dim3(256,2), 256, 0, stream>>>(abuf, W2Tb + (size_t)i*32768, 128, ep); }
    { EpArgs ep{proj_b + i*256, nullptr, tbuf, nullptr, nullptr, nullptr, nullptr, shift};
      gemm_k<M_PROJ><<<dim3(256,2), 256, 0, stream>>>(o2buf, projwb + (size_t)i*65536, 256, ep); }
    ln_k<<<8192, 256, 0, stream>>>(tbuf, ln2_g + i*256, ln2_b + i*256, zbuf, 0, 0);
    { EpArgs ep{mlp_b1 + i*512, nullptr, nullptr, gbuf, nullptr, nullptr, nullptr, 0};
      gemm_k<M_MLP1><<<dim3(256,4), 256, 0, stream>>>(zbuf, mlp1wb + (size_t)i*131072, 256, ep); }
    { EpArgs ep{mlp_b2 + i*256, nullptr, tbuf, nullptr, nullptr, nullptr, nullptr, 0};
      gemm_k<M_MLP2><<<dim3(256,2), 256, 0, stream>>>(gbuf, mlp2wb + (size_t)i*131072, 512, ep); }
  }
  nchw_k<<<512, 256, 0, stream>>>(tbuf, (float*)d_out);
}

// Round 2
// 959.557 us; speedup vs baseline: 1.1148x; 1.1148x over previous
//
#include <hip/hip_runtime.h>

// ---------------------------------------------------------------- types/helpers
using frag_ab = __attribute__((ext_vector_type(8))) short;   // bf16x8 MFMA operand
using f4v     = __attribute__((ext_vector_type(4))) float;   // MFMA accumulator
using u8v     = __attribute__((ext_vector_type(8))) unsigned short;
using u4v     = __attribute__((ext_vector_type(4))) unsigned short;

__device__ __forceinline__ float b2f(unsigned short u){
  return __uint_as_float(((unsigned int)u) << 16);
}
__device__ __forceinline__ unsigned short f2b(float f){
  unsigned int x = __float_as_uint(f);
  unsigned int r = x + 0x7fffu + ((x >> 16) & 1u);
  return (unsigned short)(r >> 16);
}
__device__ __forceinline__ float hexp2(float x){
#if __has_builtin(__builtin_amdgcn_exp2f)
  return __builtin_amdgcn_exp2f(x);
#else
  return exp2f(x);
#endif
}
__device__ __forceinline__ float hrcp(float x){
#if __has_builtin(__builtin_amdgcn_rcpf)
  return __builtin_amdgcn_rcpf(x);
#else
  return 1.0f / x;
#endif
}
__device__ __forceinline__ unsigned int cvtpk(float lo, float hi){
  unsigned int r;
  asm("v_cvt_pk_bf16_f32 %0, %1, %2" : "=v"(r) : "v"(lo), "v"(hi));
  return r;
}
// async global->LDS, 16B per lane; dest must be linear (wave base + lane*16)
__device__ __forceinline__ void gl16(const void* g, void* l){
  __builtin_amdgcn_global_load_lds(
      (const __attribute__((address_space(1))) unsigned int*)g,
      (__attribute__((address_space(3))) unsigned int*)l, 16, 0, 0);
}

#define MFMA_BF16 __builtin_amdgcn_mfma_f32_16x16x32_bf16

// ---------------------------------------------------------------- ws layout (bytes)
static constexpr size_t OFF_T   = 0;                       // t f32 [32768][256]           33,554,432
static constexpr size_t OFF_R1  = 33554432ull;             // im2col | q+k | g (mlp hidden)
static constexpr size_t OFF_V   = OFF_R1 + 37748736ull;    // o2                           16,777,216
static constexpr size_t OFF_VT  = OFF_V + 16777216ull;     // vT (permuted) | logits f32   16,777,216
static constexpr size_t OFF_ZH  = OFF_VT + 16777216ull;    // zwin | o | h                 16,777,216
static constexpr size_t OFF_A   = OFF_ZH + 16777216ull;    // a bf16 [32768][128]           8,388,608
static constexpr size_t OFF_WB  = OFF_A + 8388608ull;      // converted weights
// weight sub-offsets (bytes from OFF_WB)
static constexpr size_t WB_CONVW = 0;          // 256*576*2        =   294,912
static constexpr size_t WB_QKVW  = 294912;     // 4*768*256*2      = 1,572,864
static constexpr size_t WB_PROJW = 1867776;    // 4*256*256*2      =   524,288
static constexpr size_t WB_MLP1W = 2392064;    // 4*512*256*2      = 1,048,576
static constexpr size_t WB_MLP2W = 3440640;    // 4*256*512*2      = 1,048,576
static constexpr size_t WB_W1    = 4489216;    // 4*128*256*2      =   262,144
static constexpr size_t WB_W2T   = 4751360;    // 4*256*128*2      =   262,144
static constexpr size_t WB_BLOG  = 5013504;    // 4*128*4 f32      =     2,048
static constexpr size_t WB_CS    = 5015552;    // 256 f32
static constexpr size_t WB_CSH   = 5016576;    // 256 f32
static constexpr size_t WB_BIASP = 5017600;    // 10 tbl * 4 h * 65536 * 2 = 5,242,880 (premasked, *log2e)

// table base index per layer (layers 0,2: 1 table; layers 1,3: 4 variants)
// t0->(L0,v0)  t1..4->(L1,v0..3)  t5->(L2,v0)  t6..9->(L3,v0..3)

// ---------------------------------------------------------------- prep
__global__ __launch_bounds__(256) void prep_k(
    const float* __restrict__ conv_w, const float* __restrict__ bn_g, const float* __restrict__ bn_b,
    const float* __restrict__ bn_m, const float* __restrict__ bn_v,
    const float* __restrict__ qkv_w, const float* __restrict__ proj_w,
    const float* __restrict__ mlp_w1, const float* __restrict__ mlp_w2,
    const float* __restrict__ mem_b, const float* __restrict__ down_w, const float* __restrict__ down_b,
    const float* __restrict__ up_w, const float* __restrict__ rpb,
    unsigned short* convwb, unsigned short* qkvwb, unsigned short* projwb,
    unsigned short* mlp1wb, unsigned short* mlp2wb, unsigned short* W1b, unsigned short* W2Tb,
    unsigned short* biasPb, float* blogf, float* convS, float* convSh)
{
  int idx = blockIdx.x * 256 + threadIdx.x;
  if (idx < 256){
    float s = bn_g[idx] * rsqrtf(bn_v[idx] + 1e-5f);
    convS[idx] = s; convSh[idx] = bn_b[idx] - bn_m[idx] * s; return;
  }
  idx -= 256;
  if (idx < 147456){  // conv weight reorder: [co][ci*9+ky*3+kx]
    int co = idx / 576, kk = idx % 576;
    int ci = kk / 9, t9 = kk % 9, ky = t9 / 3, kx = t9 % 3;
    convwb[idx] = f2b(conv_w[((co*64 + ci)*3 + ky)*3 + kx]); return;
  }
  idx -= 147456;
  if (idx < 786432){ qkvwb[idx] = f2b(qkv_w[idx]); return; }
  idx -= 786432;
  if (idx < 262144){ projwb[idx] = f2b(proj_w[idx]); return; }
  idx -= 262144;
  if (idx < 524288){ mlp1wb[idx] = f2b(mlp_w1[idx]); return; }
  idx -= 524288;
  if (idx < 524288){ mlp2wb[idx] = f2b(mlp_w2[idx]); return; }
  idx -= 524288;
  if (idx < 131072){  // W1[i][s][c] = sum_j mem[i][s][j]*down[i][j][c]
    int i = idx >> 15, rem = idx & 32767, s = rem >> 8, c = rem & 255;
    float acc = 0.f;
    for (int j = 0; j < 32; ++j) acc += mem_b[(i*128 + s)*32 + j] * down_w[(i*32 + j)*256 + c];
    W1b[idx] = f2b(acc); return;
  }
  idx -= 131072;
  if (idx < 131072){  // W2T[i][c][s] = sum_j mem[i][s][j]*up[i][c][j]
    int i = idx >> 15, rem = idx & 32767, c = rem >> 7, s = rem & 127;
    float acc = 0.f;
    for (int j = 0; j < 32; ++j) acc += mem_b[(i*128 + s)*32 + j] * up_w[(i*256 + c)*32 + j];
    W2Tb[idx] = f2b(acc); return;
  }
  idx -= 131072;
  if (idx < 512){  // blog[i][s] = mem[i][s]·down_b[i]
    int i = idx >> 7, s = idx & 127;
    float acc = 0.f;
    for (int j = 0; j < 32; ++j) acc += mem_b[(i*128 + s)*32 + j] * down_b[i*32 + j];
    blogf[idx] = acc; return;
  }
  idx -= 512;
  if (idx < 2621440){  // premasked bias tables, [t][h][n_query][m_key], * log2(e)
    int t = idx >> 18, h = (idx >> 16) & 3, n = (idx >> 8) & 255, m = idx & 255;
    int layer, var;
    if (t == 0){ layer = 0; var = 0; }
    else if (t <= 4){ layer = 1; var = t - 1; }
    else if (t == 5){ layer = 2; var = 0; }
    else { layer = 3; var = t - 6; }
    int rn = n >> 4, cn = n & 15, rm = m >> 4, cm = m & 15;
    int ri = (rn - rm + 15)*31 + (cn - cm + 15);
    float b = rpb[((size_t)layer*961 + ri)*4 + h];
    bool mk = ((var & 2) && ((rn < 8) != (rm < 8))) || ((var & 1) && ((cn < 8) != (cm < 8)));
    if (mk) b -= 100.0f;
    biasPb[idx] = f2b(b * 1.44269504f);
  }
}

// ---------------------------------------------------------------- im2col (k-order ci*9+ky*3+kx), f32 -> bf16
__global__ __launch_bounds__(256) void im2col_k(const float* __restrict__ x, unsigned short* __restrict__ col)
{
  int idx = blockIdx.x * 256 + threadIdx.x;   // 32768*576
  if (idx >= 32768*576) return;
  int row = idx / 576, kk = idx % 576;
  int ci = kk / 9, t9 = kk % 9, ky = t9 / 3, kx = t9 % 3;
  int b = row >> 12, hh = (row >> 6) & 63, wp = row & 63;
  int h2 = hh + ky - 1, w2 = wp + kx - 1;
  float v = 0.f;
  if (h2 >= 0 && h2 < 64 && w2 >= 0 && w2 < 64) v = x[((b*64 + ci)*64 + h2)*64 + w2];
  col[idx] = f2b(v);
}

// ---------------------------------------------------------------- GEMM: Y[M,N] = X[M,K](bf16) @ W[N,K]^T(bf16), fused epilogues
struct EpArgs {
  const float* b0; const float* b1;
  float* f0;
  unsigned short* u0; unsigned short* u1; unsigned short* u2;
  const unsigned short* uin;
  int shift;
};
enum { M_CONV=0, M_QKV=1, M_MEM1=2, M_MEM2=3, M_PROJ=4, M_MLP1=5, M_MLP2=6 };

template<int MODE>
__global__ __launch_bounds__(256) void gemm_k(const unsigned short* __restrict__ X,
                                              const unsigned short* __restrict__ W,
                                              int K, EpArgs ep)
{
  __shared__ __align__(16) unsigned short Als[128*32];
  __shared__ __align__(16) unsigned short Bls[128*32];
  const int tid = threadIdx.x;
  const int wid = tid >> 6, lane = tid & 63, g = lane >> 4, l15 = lane & 15;
  const int wr = wid >> 1, wc = wid & 1;
  const int row0 = blockIdx.x * 128, col0 = blockIdx.y * 128;
  const int KT = K >> 5;
  const int s0 = tid, s1 = tid + 256;
  const int rS0 = s0 >> 2, pS0 = s0 & 3, lb0 = pS0 ^ ((rS0 >> 1) & 3);
  const int rS1 = s1 >> 2, pS1 = s1 & 3, lb1 = pS1 ^ ((rS1 >> 1) & 3);
  const unsigned short* gA0 = &X[(size_t)(row0 + rS0)*K + lb0*8];
  const unsigned short* gA1 = &X[(size_t)(row0 + rS1)*K + lb1*8];
  const unsigned short* gB0 = &W[(size_t)(col0 + rS0)*K + lb0*8];
  const unsigned short* gB1 = &W[(size_t)(col0 + rS1)*K + lb1*8];

  f4v acc[4][4] = {};

  for (int kt = 0; kt < KT; ++kt){
    __syncthreads();
    gl16(gA0 + kt*32, &Als[s0*8]);
    gl16(gA1 + kt*32, &Als[s1*8]);
    gl16(gB0 + kt*32, &Bls[s0*8]);
    gl16(gB1 + kt*32, &Bls[s1*8]);
    __syncthreads();   // compiler drains vmcnt(0) here
    frag_ab af[4], bfv[4];
    #pragma unroll
    for (int a = 0; a < 4; ++a){ int r = wr*64 + a*16 + l15; int pb = g ^ ((r >> 1) & 3);
      af[a] = *(const frag_ab*)&Als[r*32 + pb*8]; }
    #pragma unroll
    for (int b = 0; b < 4; ++b){ int r = wc*64 + b*16 + l15; int pb = g ^ ((r >> 1) & 3);
      bfv[b] = *(const frag_ab*)&Bls[r*32 + pb*8]; }
    #pragma unroll
    for (int a = 0; a < 4; ++a)
      #pragma unroll
      for (int b = 0; b < 4; ++b)
        acc[a][b] = MFMA_BF16(af[a], bfv[b], acc[a][b], 0, 0, 0);
  }

  #pragma unroll
  for (int a = 0; a < 4; ++a){
    #pragma unroll
    for (int b = 0; b < 4; ++b){
      const int grow0 = row0 + wr*64 + a*16 + g*4;      // +r, r=0..3
      const int gcol  = col0 + wc*64 + b*16 + l15;
      if constexpr (MODE == M_QKV){
        int which = gcol >> 8, hh = (gcol >> 6) & 3, hd = gcol & 63;
        if (which == 2){
          // V: write transposed + slot-permuted: vt[(win*4+head)][hd][pos(tok)]
          int win = grow0 >> 8, tok0 = grow0 & 255;
          int pos = (tok0 & ~31) | ((tok0 & 12) << 1) | ((tok0 & 16) >> 2);
          float bv = ep.b0[gcol];
          u4v o;
          #pragma unroll
          for (int r = 0; r < 4; ++r) o[r] = f2b(acc[a][b][r] + bv);
          *(u4v*)&ep.u2[(((size_t)(win*4 + hh)*64 + hd)*256) + pos] = o;
        } else {
          unsigned short* dst = (which == 0) ? ep.u0 : ep.u1;
          float sc = (which == 0) ? 0.18033688f : 1.0f;   // 0.125 * log2(e) folded into Q
          float bv = ep.b0[gcol];
          #pragma unroll
          for (int r = 0; r < 4; ++r){
            int grow = grow0 + r;
            dst[(((size_t)(grow >> 8)*4 + hh)*256 + (grow & 255))*64 + hd] = f2b((acc[a][b][r] + bv) * sc);
          }
        }
      } else {
        #pragma unroll
        for (int r = 0; r < 4; ++r){
          int grow = grow0 + r;
          float v = acc[a][b][r];
          if constexpr (MODE == M_CONV){
            ep.f0[(size_t)grow*256 + gcol] = fmaxf(v * ep.b0[gcol] + ep.b1[gcol], 0.f);
          } else if constexpr (MODE == M_MEM1){
            ep.f0[(size_t)grow*128 + gcol] = v + ep.b0[gcol];
          } else if constexpr (MODE == M_MEM2){
            size_t ix = (size_t)grow*256 + gcol;
            ep.u0[ix] = f2b(b2f(ep.uin[ix]) + 0.1f*(v + ep.b0[gcol]));
          } else if constexpr (MODE == M_PROJ){
            float vb = v + ep.b0[gcol];
            int win = grow >> 8, tok = grow & 255;
            int bb = win >> 4, wh = (win >> 2) & 3, ww = win & 3, rr = tok >> 4, cc = tok & 15;
            int h = (wh*16 + rr + ep.shift) & 63, w2 = (ww*16 + cc + ep.shift) & 63;
            ep.f0[((size_t)((bb*64 + h)*64 + w2))*256 + gcol] += vb;
          } else if constexpr (MODE == M_MLP1){
            float xq = v + ep.b0[gcol];
            // gelu(tanh approx): x * (1 - 1/(exp2(c1*x + c2*x^3) + 1))
            float x3 = xq*xq*xq;
            float e = hexp2(xq*2.3022115f + x3*0.10294856f);
            float gl = xq - xq*hrcp(e + 1.0f);
            ep.u0[(size_t)grow*512 + gcol] = f2b(gl);
          } else { // M_MLP2
            ep.f0[(size_t)grow*256 + gcol] += v + ep.b0[gcol];
          }
        }
      }
    }
  }
}

// ---------------------------------------------------------------- LayerNorm (wave per token), optional roll+window gather
__global__ __launch_bounds__(256) void ln_k(const float* __restrict__ t, const float* __restrict__ gw,
    const float* __restrict__ bw, unsigned short* __restrict__ o, int windowed, int shift)
{
  int row = blockIdx.x*4 + (threadIdx.x >> 6);
  int lane = threadIdx.x & 63;
  size_t src;
  if (windowed){
    int win = row >> 8, tok = row & 255;
    int b = win >> 4, wh = (win >> 2) & 3, ww = win & 3, r = tok >> 4, c = tok & 15;
    int h = (wh*16 + r + shift) & 63, w2 = (ww*16 + c + shift) & 63;
    src = ((size_t)((b*64 + h)*64 + w2))*256;
  } else {
    src = (size_t)row*256;
  }
  float4 x = *(const float4*)&t[src + lane*4];
  float s1 = x.x + x.y + x.z + x.w;
  float s2 = x.x*x.x + x.y*x.y + x.z*x.z + x.w*x.w;
  #pragma unroll
  for (int d = 1; d < 64; d <<= 1){ s1 += __shfl_xor(s1, d); s2 += __shfl_xor(s2, d); }
  float mu = s1 * (1.0f/256.0f);
  float var = s2 * (1.0f/256.0f) - mu*mu;
  float rs = rsqrtf(var + 1e-5f);
  int c0 = lane*4;
  float xs[4] = {x.x, x.y, x.z, x.w};
  u4v ov;
  #pragma unroll
  for (int e = 0; e < 4; ++e) ov[e] = f2b((xs[e]-mu)*rs*gw[c0+e] + bw[c0+e]);
  *(u4v*)&o[(size_t)row*256 + c0] = ov;
}

// ---------------------------------------------------------------- windowed attention, one block per (win,head), 4 waves
// S^T = mfma(K, Q): lane owns one query; premasked bias tables; no max pass; PV in-register.
__global__ __launch_bounds__(256) void attn_k(const unsigned short* __restrict__ qg_,
    const unsigned short* __restrict__ kg_, const unsigned short* __restrict__ vt_,
    const unsigned short* __restrict__ biasP, unsigned short* __restrict__ ob, int shift)
{
  __shared__ __align__(16) unsigned short Kl[16384];   // [256 tok][64 hd], 8-chunk XOR by row&7
  __shared__ __align__(16) unsigned short Vl[16384];   // [64 hd][256 tok(permuted)], 16B-chunk XOR by hd&15
  const int tid = threadIdx.x, wid = tid >> 6, lane = tid & 63, g = lane >> 4, q15 = lane & 15;
  const int blk = blockIdx.x, win = blk >> 2, head = blk & 3;
  const int wh = (win >> 2) & 3, ww = win & 3;
  const unsigned short* kg = kg_ + (size_t)blk*16384;
  const unsigned short* vg = vt_ + (size_t)blk*16384;
  const unsigned short* qg = qg_ + (size_t)blk*16384;
  const int var = shift ? (((wh == 3) ? 2 : 0) | ((ww == 3) ? 1 : 0)) : 0;
  const unsigned short* bT = biasP + ((size_t)var*4 + head)*65536;

  #pragma unroll
  for (int it = 0; it < 8; ++it){
    int s = it*256 + tid;
    int r = s >> 3, lb = (s & 7) ^ (r & 7);
    gl16(&kg[r*64 + lb*8], &Kl[s*8]);
    int hd = s >> 5, cc = s & 31, cs = (cc & 16) | ((cc & 15) ^ (hd & 15));
    gl16(&vg[hd*256 + cs*8], &Vl[s*8]);
  }
  __syncthreads();

  const f4v Z4 = {0.f, 0.f, 0.f, 0.f};
  for (int c = 0; c < 4; ++c){
    const int nq = wid*64 + c*16 + q15;         // this lane's query token
    frag_ab qf0 = *(const frag_ab*)&qg[nq*64 + g*8];
    frag_ab qf1 = *(const frag_ab*)&qg[nq*64 + 32 + g*8];
    f4v acc[16];
    #pragma unroll
    for (int t2 = 0; t2 < 16; ++t2) acc[t2] = Z4;
    #pragma unroll
    for (int t2 = 0; t2 < 16; ++t2){
      int r = t2*16 + q15;
      { int pb = g ^ (r & 7);
        frag_ab ak = *(const frag_ab*)&Kl[r*64 + pb*8];
        acc[t2] = MFMA_BF16(ak, qf0, acc[t2], 0, 0, 0); }
      { int pb = (4 + g) ^ (r & 7);
        frag_ab ak = *(const frag_ab*)&Kl[r*64 + pb*8];
        acc[t2] = MFMA_BF16(ak, qf1, acc[t2], 0, 0, 0); }
    }
    // softmax: p = exp2(s2 + bias2), no max pass (logits bounded; mask = -144 underflows)
    const u4v* bp = (const u4v*)(bT + (size_t)nq*256);
    float vsum = 0.f;
    #pragma unroll
    for (int t2 = 0; t2 < 16; ++t2){
      u4v bb = bp[t2*4 + g];
      #pragma unroll
      for (int r = 0; r < 4; ++r){
        float p = hexp2(acc[t2][r] + b2f(bb[r]));
        acc[t2][r] = p; vsum += p;
      }
    }
    vsum += __shfl_xor(vsum, 16);
    vsum += __shfl_xor(vsum, 32);
    float inv = 1.0f / vsum;
    float invl[4];
    #pragma unroll
    for (int r = 0; r < 4; ++r) invl[r] = __shfl(inv, g*4 + r);
    // PV: pa slot e <-> k = 32s + (e>>2)*16 + g*4 + (e&3); V pre-permuted so this is contiguous
    f4v oc[4];
    #pragma unroll
    for (int nn = 0; nn < 4; ++nn) oc[nn] = Z4;
    #pragma unroll
    for (int s = 0; s < 8; ++s){
      union { frag_ab f; unsigned int u[4]; } pa;
      pa.u[0] = cvtpk(acc[2*s][0],   acc[2*s][1]);
      pa.u[1] = cvtpk(acc[2*s][2],   acc[2*s][3]);
      pa.u[2] = cvtpk(acc[2*s+1][0], acc[2*s+1][1]);
      pa.u[3] = cvtpk(acc[2*s+1][2], acc[2*s+1][3]);
      #pragma unroll
      for (int nn = 0; nn < 4; ++nn){
        int hd = nn*16 + q15;
        int cc = s*4 + g;
        int cs = (cc & 16) | ((cc & 15) ^ (hd & 15));
        frag_ab bv = *(const frag_ab*)&Vl[hd*256 + cs*8];
        oc[nn] = MFMA_BF16(pa.f, bv, oc[nn], 0, 0, 0);
      }
    }
    #pragma unroll
    for (int nn = 0; nn < 4; ++nn)
      #pragma unroll
      for (int r = 0; r < 4; ++r){
        int qq = wid*64 + c*16 + g*4 + r;
        ob[((size_t)(win*256 + qq))*256 + head*64 + nn*16 + q15] = f2b(oc[nn][r] * invl[r]);
      }
  }
}

// ---------------------------------------------------------------- softmax over 128 memory slots, wave per token
__global__ __launch_bounds__(256) void sm128_k(const float* __restrict__ lg, unsigned short* __restrict__ a)
{
  int row = blockIdx.x*4 + (threadIdx.x >> 6), lane = threadIdx.x & 63;
  float2 lv = *(const float2*)&lg[(size_t)row*128 + lane*2];
  float m = fmaxf(lv.x, lv.y);
  #pragma unroll
  for (int d = 1; d < 64; d <<= 1) m = fmaxf(m, __shfl_xor(m, d));
  float e0 = exp2f((lv.x - m)*1.44269504f), e1 = exp2f((lv.y - m)*1.44269504f);
  float s = e0 + e1;
  #pragma unroll
  for (int d = 1; d < 64; d <<= 1) s += __shfl_xor(s, d);
  float inv = 1.0f / s;
  unsigned int pack = ((unsigned int)f2b(e1*inv) << 16) | f2b(e0*inv);
  *(unsigned int*)&a[(size_t)row*128 + lane*2] = pack;
}

// ---------------------------------------------------------------- final NHWC f32 -> NCHW f32
__global__ __launch_bounds__(256) void nchw_k(const float* __restrict__ t, float* __restrict__ out)
{
  __shared__ float ls[64*65];
  int bh = blockIdx.x; int b = bh >> 6, h = bh & 63; int tid = threadIdx.x;
  for (int c0 = 0; c0 < 256; c0 += 64){
    #pragma unroll
    for (int rr = 0; rr < 4; ++rr){
      int s = rr*256 + tid;
      int w = s >> 4, c4 = s & 15;
      float4 v = *(const float4*)&t[((size_t)((b*64 + h)*64 + w))*256 + c0 + c4*4];
      ls[w*65 + c4*4 + 0] = v.x; ls[w*65 + c4*4 + 1] = v.y;
      ls[w*65 + c4*4 + 2] = v.z; ls[w*65 + c4*4 + 3] = v.w;
    }
    __syncthreads();
    int c = tid & 63, wq = tid >> 6;
    float buf[16];
    #pragma unroll
    for (int k2 = 0; k2 < 16; ++k2) buf[k2] = ls[(wq*16 + k2)*65 + c];
    size_t obase = ((size_t)(b*256 + c0 + c))*4096 + h*64 + wq*16;
    #pragma unroll
    for (int k2 = 0; k2 < 16; k2 += 4){
      float4 o4 = make_float4(buf[k2], buf[k2+1], buf[k2+2], buf[k2+3]);
      *(float4*)&out[obase + k2] = o4;
    }
    __syncthreads();
  }
}

// ---------------------------------------------------------------- host
extern "C" void kernel_launch(void* const* d_in, const int* in_sizes, int n_in,
                              void* d_out, int out_size, void* d_ws, size_t ws_size,
                              hipStream_t stream)
{
  (void)in_sizes; (void)n_in; (void)out_size; (void)ws_size;
  const float* x      = (const float*)d_in[0];
  const float* conv_w = (const float*)d_in[1];
  const float* bn_g   = (const float*)d_in[2];
  const float* bn_b   = (const float*)d_in[3];
  const float* bn_m   = (const float*)d_in[4];
  const float* bn_v   = (const float*)d_in[5];
  const float* ln1_g  = (const float*)d_in[6];
  const float* ln1_b  = (const float*)d_in[7];
  const float* qkv_w  = (const float*)d_in[8];
  const float* qkv_b  = (const float*)d_in[9];
  const float* proj_w = (const float*)d_in[10];
  const float* proj_b = (const float*)d_in[11];
  const float* rpb    = (const float*)d_in[12];
  const float* mem_b  = (const float*)d_in[13];
  const float* down_w = (const float*)d_in[14];
  const float* down_b = (const float*)d_in[15];
  const float* up_w   = (const float*)d_in[16];
  const float* up_b   = (const float*)d_in[17];
  const float* ln2_g  = (const float*)d_in[18];
  const float* ln2_b  = (const float*)d_in[19];
  const float* mlp_w1 = (const float*)d_in[20];
  const float* mlp_b1 = (const float*)d_in[21];
  const float* mlp_w2 = (const float*)d_in[22];
  const float* mlp_b2 = (const float*)d_in[23];

  char* ws = (char*)d_ws;
  float*          tbuf  = (float*)(ws + OFF_T);
  unsigned short* colb  = (unsigned short*)(ws + OFF_R1);
  unsigned short* qbuf  = (unsigned short*)(ws + OFF_R1);
  unsigned short* kbuf  = (unsigned short*)(ws + OFF_R1 + 16777216ull);
  unsigned short* gbuf  = (unsigned short*)(ws + OFF_R1);
  unsigned short* o2buf = (unsigned short*)(ws + OFF_V);
  unsigned short* vtbuf = (unsigned short*)(ws + OFF_VT);
  float*          logb  = (float*)(ws + OFF_VT);
  unsigned short* zbuf  = (unsigned short*)(ws + OFF_ZH);  // zwin | o | h
  unsigned short* abuf  = (unsigned short*)(ws + OFF_A);
  unsigned short* convwb = (unsigned short*)(ws + OFF_WB + WB_CONVW);
  unsigned short* qkvwb  = (unsigned short*)(ws + OFF_WB + WB_QKVW);
  unsigned short* projwb = (unsigned short*)(ws + OFF_WB + WB_PROJW);
  unsigned short* mlp1wb = (unsigned short*)(ws + OFF_WB + WB_MLP1W);
  unsigned short* mlp2wb = (unsigned short*)(ws + OFF_WB + WB_MLP2W);
  unsigned short* W1b    = (unsigned short*)(ws + OFF_WB + WB_W1);
  unsigned short* W2Tb   = (unsigned short*)(ws + OFF_WB + WB_W2T);
  float*          blogf  = (float*)(ws + OFF_WB + WB_BLOG);
  float*          convS  = (float*)(ws + OFF_WB + WB_CS);
  float*          convSh = (float*)(ws + OFF_WB + WB_CSH);
  unsigned short* biasPb = (unsigned short*)(ws + OFF_WB + WB_BIASP);

  prep_k<<<20036, 256, 0, stream>>>(conv_w, bn_g, bn_b, bn_m, bn_v, qkv_w, proj_w, mlp_w1, mlp_w2,
                                    mem_b, down_w, down_b, up_w, rpb,
                                    convwb, qkvwb, projwb, mlp1wb, mlp2wb, W1b, W2Tb, biasPb,
                                    blogf, convS, convSh);
  im2col_k<<<73728, 256, 0, stream>>>(x, colb);
  { EpArgs ep{convS, convSh, tbuf, nullptr, nullptr, nullptr, nullptr, 0};
    gemm_k<M_CONV><<<dim3(256,2), 256, 0, stream>>>(colb, convwb, 576, ep); }

  static const int tb[4] = {0, 1, 5, 6};
  for (int i = 0; i < 4; ++i){
    int shift = (i & 1) ? 8 : 0;
    ln_k<<<8192, 256, 0, stream>>>(tbuf, ln1_g + i*256, ln1_b + i*256, zbuf, 1, shift);
    { EpArgs ep{qkv_b + i*768, nullptr, nullptr, qbuf, kbuf, vtbuf, nullptr, 0};
      gemm_k<M_QKV><<<dim3(256,6), 256, 0, stream>>>(zbuf, qkvwb + (size_t)i*196608, 256, ep); }
    attn_k<<<512, 256, 0, stream>>>(qbuf, kbuf, vtbuf, biasPb + (size_t)tb[i]*262144, zbuf, shift);
    { EpArgs ep{blogf + i*128, nullptr, logb, nullptr, nullptr, nullptr, nullptr, 0};
      gemm_k<M_MEM1><<<dim3(256,1), 256, 0, stream>>>(zbuf, W1b + (size_t)i*32768, 256, ep); }
    sm128_k<<<8192, 256, 0, stream>>>(logb, abuf);
    { EpArgs ep{up_b + i*256, nullptr, nullptr, o2buf, nullptr, nullptr, zbuf, 0};
      gemm_k<M_MEM2><<<dim3(256,2), 256, 0, stream>>>(abuf, W2Tb + (size_t)i*32768, 128, ep); }
    { EpArgs ep{proj_b + i*256, nullptr, tbuf, nullptr, nullptr, nullptr, nullptr, shift};
      gemm_k<M_PROJ><<<dim3(256,2), 256, 0, stream>>>(o2buf, projwb + (size_t)i*65536, 256, ep); }
    ln_k<<<8192, 256, 0, stream>>>(tbuf, ln2_g + i*256, ln2_b + i*256, zbuf, 0, 0);
    { EpArgs ep{mlp_b1 + i*512, nullptr, nullptr, gbuf, nullptr, nullptr, nullptr, 0};
      gemm_k<M_MLP1><<<dim3(256,4), 256, 0, stream>>>(zbuf, mlp1wb + (size_t)i*131072, 256, ep); }
    { EpArgs ep{mlp_b2 + i*256, nullptr, tbuf, nullptr, nullptr, nullptr, nullptr, 0};
      gemm_k<M_MLP2><<<dim3(256,2), 256, 0, stream>>>(gbuf, mlp2wb + (size_t)i*131072, 512, ep); }
  }
  nchw_k<<<512, 256, 0, stream>>>(tbuf, (float*)d_out);
}